// Round 3
// baseline (189.442 us; speedup 1.0000x reference)
//
#include <hip/hip_runtime.h>
#include <hip/hip_bf16.h>
#include <cmath>

typedef float f32x4 __attribute__((ext_vector_type(4)));
typedef float f32x16 __attribute__((ext_vector_type(16)));
typedef __bf16 bf16x8 __attribute__((ext_vector_type(8)));

#define C_IN 384
#define C_OUT 384
#define SPB 4096      // spatial per batch image (64*64)
#define NPIX 131072   // 32 * 4096 total pixels
#define BP 64         // pixels per block
#define LDK 392       // padded Xs row (bf16): 784 B, 16B-aligned

// ---------------------------------------------------------------------------
// Kernel 1: fold LN affine into the weights.
//   Wp[o][c] = bf16(W[o][c] * gamma[c]);  t1[o] = sum_c float(Wp[o][c]);
//   t2[o] = sum_c beta[c]*W[o][c] + b[o]
// ---------------------------------------------------------------------------
__global__ __launch_bounds__(128) void ppl_prep_kernel(const float* __restrict__ W,
                                                       const float* __restrict__ gamma,
                                                       const float* __restrict__ beta,
                                                       const float* __restrict__ bias,
                                                       __bf16* __restrict__ Wp,
                                                       float* __restrict__ t1,
                                                       float* __restrict__ t2) {
  const int o = blockIdx.x;
  const int t = threadIdx.x;
  const float* row = W + o * C_IN;
  float s1 = 0.f, s2 = 0.f;
  for (int c = t; c < C_IN; c += 128) {
    const float w = row[c];
    const __bf16 wq = (__bf16)(w * gamma[c]);
    Wp[o * C_IN + c] = wq;
    s1 += (float)wq;
    s2 += beta[c] * w;
  }
#pragma unroll
  for (int off = 32; off > 0; off >>= 1) {
    s1 += __shfl_down(s1, off);
    s2 += __shfl_down(s2, off);
  }
  __shared__ float red[2][2];
  if ((t & 63) == 0) { red[t >> 6][0] = s1; red[t >> 6][1] = s2; }
  __syncthreads();
  if (t == 0) {
    t1[o] = red[0][0] + red[1][0];
    t2[o] = red[0][1] + red[1][1] + bias[o];
  }
}

// fast exact-enough GELU: tanh-form via sigmoid, ~8 VALU ops, err <= ~1e-3
__device__ __forceinline__ float gelu_fast(float v) {
  const float u = 0.7978845608028654f * v * __builtin_fmaf(0.044715f * v, v, 1.0f);
  const float e = __expf(-2.0f * u);               // v_exp_f32
  return v * __builtin_amdgcn_rcpf(1.0f + e);      // v * sigmoid(2u)
}

// ---------------------------------------------------------------------------
// Kernel 2: fused stats + GEMM(32x32x16 bf16 MFMA) + LN epilogue + GELU.
//   Block = 64 pixels x all 384 outs; x read once, bf16-staged in LDS with
//   fused fp32 sum/sumsq.  Wave w owns out rows [96w, 96w+96) = 3 n-tiles.
//   k-loop: B-fragments (W') ping-pong prefetched 1 step ahead from
//   L2-resident global; A-fragments from LDS; barrier-free.
// ---------------------------------------------------------------------------
__global__ __launch_bounds__(256, 3) void ppl_fused_kernel(const float* __restrict__ x,
                                                           const __bf16* __restrict__ Wp,
                                                           const float* __restrict__ t1g,
                                                           const float* __restrict__ t2g,
                                                           float* __restrict__ out) {
  __shared__ __bf16 Xs[BP][LDK];  // pixel-major, K-contiguous
  __shared__ float ps[4][BP];
  __shared__ float pq[4][BP];
  __shared__ float mu_s[BP];
  __shared__ float rs_s[BP];

  const int tid = threadIdx.x;
  const int w = tid >> 6;
  const int lane = tid & 63;
  const int p0 = blockIdx.x * BP;
  const int b = p0 >> 12;
  const int s0 = p0 & 4095;
  const float* xbase = x + (size_t)b * (C_IN * SPB) + s0 + lane;

  // ---- stage full-K x tile (bf16) + fused LN stats; 32-wide load batches ----
  {
    float s = 0.f, q = 0.f;
    const int cb = w * 96;  // wave-contiguous 96-channel slice
#pragma unroll
    for (int i = 0; i < 3; ++i) {
      const float* xi = xbase + (size_t)(cb + i * 32) * SPB;
      float v[4][8];
#pragma unroll
      for (int g = 0; g < 4; ++g)
#pragma unroll
        for (int j = 0; j < 8; ++j)
          v[g][j] = xi[(size_t)(g * 8 + j) * SPB];  // 32 loads in flight
#pragma unroll
      for (int g = 0; g < 4; ++g) {
        bf16x8 pk;
#pragma unroll
        for (int j = 0; j < 8; ++j) {
          const float t = v[g][j];
          s += t;
          q += t * t;
          pk[j] = (__bf16)t;
        }
        *reinterpret_cast<bf16x8*>(&Xs[lane][cb + i * 32 + g * 8]) = pk;
      }
    }
    ps[w][lane] = s;
    pq[w][lane] = q;
  }
  __syncthreads();
  if (tid < BP) {
    const float st = ps[0][tid] + ps[1][tid] + ps[2][tid] + ps[3][tid];
    const float qt = pq[0][tid] + pq[1][tid] + pq[2][tid] + pq[3][tid];
    const float m = st * (1.0f / C_IN);
    mu_s[tid] = m;
    rs_s[tid] = rsqrtf(qt * (1.0f / C_IN) - m * m + 1e-5f);
  }
  __syncthreads();

  // ---- barrier-free k-loop, 32x32x16 MFMA, B ping-pong prefetch ----
  const int col = lane & 31;
  const int hi = lane >> 5;
  const int ob = w * 96;
  const __bf16* wp0 = Wp + (size_t)(ob + col) * C_IN + hi * 8;
  const __bf16* wp1 = wp0 + 32 * C_IN;
  const __bf16* wp2 = wp0 + 64 * C_IN;
  const __bf16* xs0 = &Xs[col][hi * 8];
  const __bf16* xs1 = &Xs[32 + col][hi * 8];

  f32x16 acc[2][3];
#pragma unroll
  for (int m = 0; m < 2; ++m)
#pragma unroll
    for (int n = 0; n < 3; ++n)
#pragma unroll
      for (int r = 0; r < 16; ++r) acc[m][n][r] = 0.f;

#define LOADB(dst, kk)                                   \
  {                                                      \
    dst[0] = *reinterpret_cast<const bf16x8*>(wp0 + (kk)); \
    dst[1] = *reinterpret_cast<const bf16x8*>(wp1 + (kk)); \
    dst[2] = *reinterpret_cast<const bf16x8*>(wp2 + (kk)); \
  }
#define STEP(bb, kk)                                                              \
  {                                                                               \
    const bf16x8 a0 = *reinterpret_cast<const bf16x8*>(xs0 + (kk));               \
    const bf16x8 a1 = *reinterpret_cast<const bf16x8*>(xs1 + (kk));               \
    acc[0][0] = __builtin_amdgcn_mfma_f32_32x32x16_bf16(a0, bb[0], acc[0][0], 0, 0, 0); \
    acc[0][1] = __builtin_amdgcn_mfma_f32_32x32x16_bf16(a0, bb[1], acc[0][1], 0, 0, 0); \
    acc[0][2] = __builtin_amdgcn_mfma_f32_32x32x16_bf16(a0, bb[2], acc[0][2], 0, 0, 0); \
    acc[1][0] = __builtin_amdgcn_mfma_f32_32x32x16_bf16(a1, bb[0], acc[1][0], 0, 0, 0); \
    acc[1][1] = __builtin_amdgcn_mfma_f32_32x32x16_bf16(a1, bb[1], acc[1][1], 0, 0, 0); \
    acc[1][2] = __builtin_amdgcn_mfma_f32_32x32x16_bf16(a1, bb[2], acc[1][2], 0, 0, 0); \
  }

  {
    bf16x8 bA[3], bB[3];
    LOADB(bA, 0);
#pragma unroll
    for (int it = 0; it < 12; ++it) {
      const int k = it * 32;
      LOADB(bB, k + 16);
      STEP(bA, k);
      if (it < 11) LOADB(bA, k + 32);
      STEP(bB, k + 16);
    }
  }
#undef LOADB
#undef STEP

  // ---- epilogue: LN correction + fast GELU + float4 NCHW stores ----
  const float t1v0 = t1g[ob + col], t1v1 = t1g[ob + 32 + col], t1v2 = t1g[ob + 64 + col];
  const float t2v0 = t2g[ob + col], t2v1 = t2g[ob + 32 + col], t2v2 = t2g[ob + 64 + col];
  const float t1v[3] = {t1v0, t1v1, t1v2};
  const float t2v[3] = {t2v0, t2v1, t2v2};

#pragma unroll
  for (int n = 0; n < 3; ++n) {
    float* outo = out + (((size_t)(b * C_OUT + ob + n * 32 + col)) << 12) + s0;
#pragma unroll
    for (int m = 0; m < 2; ++m) {
#pragma unroll
      for (int qd = 0; qd < 4; ++qd) {
        const int pr = m * 32 + qd * 8 + hi * 4;  // pixel base of this reg quad
        const f32x4 mu4 = *reinterpret_cast<const f32x4*>(&mu_s[pr]);
        const f32x4 rs4 = *reinterpret_cast<const f32x4*>(&rs_s[pr]);
        f32x4 y;
#pragma unroll
        for (int r = 0; r < 4; ++r) {
          const float val = rs4[r] * (acc[m][n][qd * 4 + r] - mu4[r] * t1v[n]) + t2v[n];
          y[r] = gelu_fast(val);
        }
        *reinterpret_cast<f32x4*>(outo + pr) = y;
      }
    }
  }
}

// ---------------------------------------------------------------------------
extern "C" void kernel_launch(void* const* d_in, const int* in_sizes, int n_in,
                              void* d_out, int out_size, void* d_ws, size_t ws_size,
                              hipStream_t stream) {
  const float* x = (const float*)d_in[0];
  const float* gamma = (const float*)d_in[1];
  const float* beta = (const float*)d_in[2];
  const float* W = (const float*)d_in[3];
  const float* bias = (const float*)d_in[4];
  float* out = (float*)d_out;

  __bf16* Wp = (__bf16*)d_ws;                    // 384*384 bf16
  float* t1 = (float*)(Wp + C_OUT * C_IN);       // 384 floats
  float* t2 = t1 + C_OUT;                        // 384 floats

  ppl_prep_kernel<<<C_OUT, 128, 0, stream>>>(W, gamma, beta, bias, Wp, t1, t2);
  ppl_fused_kernel<<<NPIX / BP, 256, 0, stream>>>(x, Wp, t1, t2, out);
}